// Round 1
// baseline (53.068 us; speedup 1.0000x reference)
//
#include <hip/hip_runtime.h>

// RecModel fused kernel — bf16 hi/lo split-precision MFMA path.
// B=16384, T=14, L=100000, E=16, H=50; x(241) -> fc1(200) relu -> fc2(80) relu -> fc3(2)
//
// GEMM1: K padded 241->256 (8 kt of 32), N padded 200->208 (13 nt of 16)
// GEMM2: K padded 200->224 (7 kt),       N = 80 (5 nt)
// Each fp32 value v is represented as bf16 hi + bf16 lo (lo = bf16(v - hi)):
//   A*B ~= Ah*Bh + Al*Bh + Ah*Bl  (3 MFMAs, fp32 accumulate; dropped AlBl ~ 2^-18 rel)

using u16 = unsigned short;
typedef __attribute__((ext_vector_type(8))) short short8v;
typedef __attribute__((ext_vector_type(4))) float floatx4;

constexpr int BM = 32;            // rows per block
constexpr int NBLK = 16384 / BM;  // 512

// ws layout (elements of u16)
constexpr int W1_ELEMS = 13 * 8 * 64 * 8;  // 53248
constexpr int W2_ELEMS = 5 * 7 * 64 * 8;   // 17920

__device__ __forceinline__ u16 f2bf(float f) {
  unsigned u = __float_as_uint(f);
  unsigned r = (u + 0x7fffu + ((u >> 16) & 1u)) >> 16;  // RN-even
  return (u16)r;
}
__device__ __forceinline__ float bf2f(u16 h) {
  return __uint_as_float(((unsigned)h) << 16);
}

// write one x value into A1 fragment layout: lane = kg*16 + (r&15) holds k = kt*32+kg*8+e
__device__ __forceinline__ void wrA1(u16* Ah, u16* Al, int r, int k, float v) {
  u16 hi = f2bf(v);
  u16 lo = f2bf(v - bf2f(hi));
  int kt = k >> 5, kg = (k >> 3) & 3, e = k & 7;
  int lane = kg * 16 + (r & 15);
  int idx = (((r >> 4) * 8 + kt) * 64 + lane) * 8 + e;
  Ah[idx] = hi;
  Al[idx] = lo;
}

// ---- precompute: fc1/fc2 weights -> hi/lo bf16 fragment arrays in ws ----
__global__ void build_frags(const float* __restrict__ w1, const float* __restrict__ w2,
                            u16* __restrict__ w1h, u16* __restrict__ w1l,
                            u16* __restrict__ w2h, u16* __restrict__ w2l) {
  int tid = blockIdx.x * blockDim.x + threadIdx.x;
  if (tid < 13 * 8 * 64) {  // 6656: fc1 frags
    int l = tid & 63;
    int g = tid >> 6;
    int kt = g & 7, nt = g >> 3;
    int n = nt * 16 + (l & 15);
    int kb = kt * 32 + (l >> 4) * 8;
    short8v h8, l8;
#pragma unroll
    for (int e = 0; e < 8; ++e) {
      int k = kb + e;
      float v = (n < 200 && k < 241) ? w1[n * 241 + k] : 0.f;
      u16 hi = f2bf(v);
      u16 lo = f2bf(v - bf2f(hi));
      h8[e] = (short)hi;
      l8[e] = (short)lo;
    }
    *(short8v*)&w1h[tid * 8] = h8;
    *(short8v*)&w1l[tid * 8] = l8;
  } else if (tid < 13 * 8 * 64 + 5 * 7 * 64) {  // 2240: fc2 frags
    int t2 = tid - 13 * 8 * 64;
    int l = t2 & 63;
    int g = t2 >> 6;
    int kt = g % 7, nt = g / 7;
    int n = nt * 16 + (l & 15);  // < 80
    int kb = kt * 32 + (l >> 4) * 8;
    short8v h8, l8;
#pragma unroll
    for (int e = 0; e < 8; ++e) {
      int k = kb + e;
      float v = (k < 200) ? w2[n * 200 + k] : 0.f;
      u16 hi = f2bf(v);
      u16 lo = f2bf(v - bf2f(hi));
      h8[e] = (short)hi;
      l8[e] = (short)lo;
    }
    *(short8v*)&w2h[t2 * 8] = h8;
    *(short8v*)&w2l[t2 * 8] = l8;
  }
}

// ---- main fused kernel ----
__global__ void fused_kernel(const int* __restrict__ sf, const float* __restrict__ dense,
                             const int* __restrict__ hist, const float* __restrict__ W,
                             const u16* __restrict__ w1h, const u16* __restrict__ w1l,
                             const u16* __restrict__ w2h, const u16* __restrict__ w2l,
                             const float* __restrict__ b1, const float* __restrict__ b2,
                             const float* __restrict__ w3, const float* __restrict__ b3,
                             float* __restrict__ out) {
  // single 32KB LDS region, reused: A1(h|l) -> A2(h|l) -> out2(f32)
  __shared__ u16 sm[16384];
  const int tid = threadIdx.x;
  const int row0 = blockIdx.x * BM;

  short8v z8 = {0, 0, 0, 0, 0, 0, 0, 0};
  // zero A1 (2048 16B blobs)
#pragma unroll
  for (int i = 0; i < 8; ++i) *(short8v*)&sm[(tid + i * 256) * 8] = z8;
  __syncthreads();

  u16* A1h = sm;         // [2][8][64][8]
  u16* A1l = sm + 8192;  // [2][8][64][8]

  // ---- gather phase ----
  if (tid < 128) {
    // history sum: 4 threads per row, float4 dims each
    int r = tid >> 2, q = tid & 3;
    int rg = row0 + r;
    float a0 = 0.f, a1 = 0.f, a2 = 0.f, a3 = 0.f;
    for (int h = 0; h < 50; ++h) {
      int idx = hist[rg * 50 + h] + 1;  // in [1, 100000]; W0 row 0 never hit
      const float* p = W + (size_t)idx * 16 + q * 4;
      a0 += p[0];
      a1 += p[1];
      a2 += p[2];
      a3 += p[3];
    }
    float vals[4] = {a0, a1, a2, a3};
#pragma unroll
    for (int j = 0; j < 4; ++j) wrA1(A1h, A1l, r, 224 + q * 4 + j, vals[j]);
    if (q == 0) wrA1(A1h, A1l, r, 240, dense[rg]);
    // k in [241,256) stays zero from the memset
  } else {
    // embeddings: 4 threads per row (dim quad), loop 14 tables
    int t2 = tid - 128;
    int r = t2 >> 2, q = t2 & 3;
    int rg = row0 + r;
    for (int t = 0; t < 14; ++t) {
      int idx = sf[rg * 14 + t] + 1;
      const float* p = W + ((size_t)t * 100001 + (size_t)idx) * 16 + q * 4;
      float v0 = p[0], v1 = p[1], v2 = p[2], v3 = p[3];
      int kb = t * 16 + q * 4;
      wrA1(A1h, A1l, r, kb + 0, v0);
      wrA1(A1h, A1l, r, kb + 1, v1);
      wrA1(A1h, A1l, r, kb + 2, v2);
      wrA1(A1h, A1l, r, kb + 3, v3);
    }
  }
  __syncthreads();

  // ---- GEMM1: 4 waves; wave = (row-half rh) x (nt parity par) ----
  const int l = tid & 63;
  const int wv = tid >> 6;
  const int rh = wv & 1;
  const int par = wv >> 1;

  floatx4 acc[7];
#pragma unroll
  for (int i = 0; i < 7; ++i) acc[i] = (floatx4){0.f, 0.f, 0.f, 0.f};

#pragma unroll
  for (int kt = 0; kt < 8; ++kt) {
    short8v ah = *(const short8v*)&A1h[((rh * 8 + kt) * 64 + l) * 8];
    short8v al = *(const short8v*)&A1l[((rh * 8 + kt) * 64 + l) * 8];
#pragma unroll
    for (int i = 0; i < 7; ++i) {
      int nt = par + 2 * i;
      if (nt < 13) {
        short8v bh = *(const short8v*)&w1h[((nt * 8 + kt) * 64 + l) * 8];
        short8v bl = *(const short8v*)&w1l[((nt * 8 + kt) * 64 + l) * 8];
        acc[i] = __builtin_amdgcn_mfma_f32_16x16x32_bf16(ah, bh, acc[i], 0, 0, 0);
        acc[i] = __builtin_amdgcn_mfma_f32_16x16x32_bf16(al, bh, acc[i], 0, 0, 0);
        acc[i] = __builtin_amdgcn_mfma_f32_16x16x32_bf16(ah, bl, acc[i], 0, 0, 0);
      }
    }
  }
  __syncthreads();

  // zero A2 region (1792 blobs = 14336 u16)
#pragma unroll
  for (int i = 0; i < 7; ++i) *(short8v*)&sm[(tid + i * 256) * 8] = z8;
  __syncthreads();

  u16* A2h = sm;         // [2][7][64][8]
  u16* A2l = sm + 7168;  // [2][7][64][8]

  // epilogue1: bias + relu -> A2 fragments (hi/lo). C layout: col=lane&15, row=(lane>>4)*4+reg
#pragma unroll
  for (int i = 0; i < 7; ++i) {
    int nt = par + 2 * i;
    if (nt < 13) {
      int n = nt * 16 + (l & 15);
      if (n < 200) {
        float bias = b1[n];
#pragma unroll
        for (int rg_ = 0; rg_ < 4; ++rg_) {
          float v = fmaxf(acc[i][rg_] + bias, 0.f);
          int m = (l >> 4) * 4 + rg_;
          u16 hi = f2bf(v);
          u16 lo = f2bf(v - bf2f(hi));
          int kt = n >> 5, kg = (n >> 3) & 3, e = n & 7;
          int lane2 = kg * 16 + m;
          int idx = ((rh * 7 + kt) * 64 + lane2) * 8 + e;
          A2h[idx] = hi;
          A2l[idx] = lo;
        }
      }
    }
  }
  __syncthreads();

  // ---- GEMM2 ----
  floatx4 acc2[3];
#pragma unroll
  for (int i = 0; i < 3; ++i) acc2[i] = (floatx4){0.f, 0.f, 0.f, 0.f};

#pragma unroll
  for (int kt = 0; kt < 7; ++kt) {
    short8v ah = *(const short8v*)&A2h[((rh * 7 + kt) * 64 + l) * 8];
    short8v al = *(const short8v*)&A2l[((rh * 7 + kt) * 64 + l) * 8];
#pragma unroll
    for (int i = 0; i < 3; ++i) {
      int nt = par + 2 * i;
      if (nt < 5) {
        short8v bh = *(const short8v*)&w2h[((nt * 7 + kt) * 64 + l) * 8];
        short8v bl = *(const short8v*)&w2l[((nt * 7 + kt) * 64 + l) * 8];
        acc2[i] = __builtin_amdgcn_mfma_f32_16x16x32_bf16(ah, bh, acc2[i], 0, 0, 0);
        acc2[i] = __builtin_amdgcn_mfma_f32_16x16x32_bf16(al, bh, acc2[i], 0, 0, 0);
        acc2[i] = __builtin_amdgcn_mfma_f32_16x16x32_bf16(ah, bl, acc2[i], 0, 0, 0);
      }
    }
  }
  __syncthreads();

  // epilogue2: bias + relu -> out2 f32 LDS [32][81] (padded stride)
  float* o2 = (float*)sm;
#pragma unroll
  for (int i = 0; i < 3; ++i) {
    int nt = par + 2 * i;
    if (nt < 5) {
      int n = nt * 16 + (l & 15);  // < 80
      float bias = b2[n];
#pragma unroll
      for (int rg_ = 0; rg_ < 4; ++rg_) {
        int r = rh * 16 + (l >> 4) * 4 + rg_;
        float v = fmaxf(acc2[i][rg_] + bias, 0.f);
        o2[r * 81 + n] = v;
      }
    }
  }
  __syncthreads();

  // ---- fc3 (fp32 VALU) ----
  if (tid < 64) {
    int r = tid >> 1, o = tid & 1;
    float a = b3[o];
#pragma unroll 8
    for (int j = 0; j < 80; ++j) a += o2[r * 81 + j] * w3[o * 80 + j];
    out[(row0 + r) * 2 + o] = a;
  }
}

extern "C" void kernel_launch(void* const* d_in, const int* in_sizes, int n_in,
                              void* d_out, int out_size, void* d_ws, size_t ws_size,
                              hipStream_t stream) {
  const int* sf = (const int*)d_in[0];
  const float* dense = (const float*)d_in[1];
  const int* hist = (const int*)d_in[2];
  const float* W = (const float*)d_in[3];
  const float* w1 = (const float*)d_in[4];
  const float* b1 = (const float*)d_in[5];
  const float* w2 = (const float*)d_in[6];
  const float* b2 = (const float*)d_in[7];
  const float* w3 = (const float*)d_in[8];
  const float* b3 = (const float*)d_in[9];
  float* out = (float*)d_out;

  // ws: w1h | w1l | w2h | w2l  (284,672 bytes total)
  u16* w1h = (u16*)d_ws;
  u16* w1l = w1h + W1_ELEMS;
  u16* w2h = w1l + W1_ELEMS;
  u16* w2l = w2h + W2_ELEMS;

  build_frags<<<dim3(35), dim3(256), 0, stream>>>(w1, w2, w1h, w1l, w2h, w2l);
  fused_kernel<<<dim3(NBLK), dim3(256), 0, stream>>>(sf, dense, hist, W, w1h, w1l, w2h, w2l,
                                                     b1, b2, w3, b3, out);
}

// Round 2
// 36.568 us; speedup vs baseline: 1.4512x; 1.4512x over previous
//
#include <hip/hip_runtime.h>

// RecModel fused kernel — bf16 hi/lo split-precision MFMA path, round 2.
// Changes vs round 1: 512-thread blocks (16 waves/CU), balanced gather phase,
// explicit register double-buffering of GEMM B-operands (depth-4 / depth-2).

using u16 = unsigned short;
typedef __attribute__((ext_vector_type(8))) short short8v;
typedef __attribute__((ext_vector_type(4))) float floatx4;

constexpr int BM = 32;            // rows per block
constexpr int NBLK = 16384 / BM;  // 512

// ws layout (elements of u16)
constexpr int W1_ELEMS = 13 * 8 * 64 * 8;  // 53248
constexpr int W2_ELEMS = 5 * 7 * 64 * 8;   // 17920

__device__ __forceinline__ u16 f2bf(float f) {
  unsigned u = __float_as_uint(f);
  unsigned r = (u + 0x7fffu + ((u >> 16) & 1u)) >> 16;  // RN-even
  return (u16)r;
}
__device__ __forceinline__ float bf2f(u16 h) {
  return __uint_as_float(((unsigned)h) << 16);
}

// write one x value into A1 fragment layout: lane = kg*16 + (r&15) holds k = kt*32+kg*8+e
__device__ __forceinline__ void wrA1(u16* Ah, u16* Al, int r, int k, float v) {
  u16 hi = f2bf(v);
  u16 lo = f2bf(v - bf2f(hi));
  int kt = k >> 5, kg = (k >> 3) & 3, e = k & 7;
  int lane = kg * 16 + (r & 15);
  int idx = (((r >> 4) * 8 + kt) * 64 + lane) * 8 + e;
  Ah[idx] = hi;
  Al[idx] = lo;
}

// ---- precompute: fc1/fc2 weights -> hi/lo bf16 fragment arrays in ws ----
__global__ void build_frags(const float* __restrict__ w1, const float* __restrict__ w2,
                            u16* __restrict__ w1h, u16* __restrict__ w1l,
                            u16* __restrict__ w2h, u16* __restrict__ w2l) {
  int tid = blockIdx.x * blockDim.x + threadIdx.x;
  if (tid < 13 * 8 * 64) {  // 6656: fc1 frags
    int l = tid & 63;
    int g = tid >> 6;
    int kt = g & 7, nt = g >> 3;
    int n = nt * 16 + (l & 15);
    int kb = kt * 32 + (l >> 4) * 8;
    short8v h8, l8;
#pragma unroll
    for (int e = 0; e < 8; ++e) {
      int k = kb + e;
      float v = (n < 200 && k < 241) ? w1[n * 241 + k] : 0.f;
      u16 hi = f2bf(v);
      u16 lo = f2bf(v - bf2f(hi));
      h8[e] = (short)hi;
      l8[e] = (short)lo;
    }
    *(short8v*)&w1h[tid * 8] = h8;
    *(short8v*)&w1l[tid * 8] = l8;
  } else if (tid < 13 * 8 * 64 + 5 * 7 * 64) {  // 2240: fc2 frags
    int t2 = tid - 13 * 8 * 64;
    int l = t2 & 63;
    int g = t2 >> 6;
    int kt = g % 7, nt = g / 7;
    int n = nt * 16 + (l & 15);  // < 80
    int kb = kt * 32 + (l >> 4) * 8;
    short8v h8, l8;
#pragma unroll
    for (int e = 0; e < 8; ++e) {
      int k = kb + e;
      float v = (k < 200) ? w2[n * 200 + k] : 0.f;
      u16 hi = f2bf(v);
      u16 lo = f2bf(v - bf2f(hi));
      h8[e] = (short)hi;
      l8[e] = (short)lo;
    }
    *(short8v*)&w2h[t2 * 8] = h8;
    *(short8v*)&w2l[t2 * 8] = l8;
  }
}

// ---- main fused kernel ----
__global__ __launch_bounds__(512, 4) void fused_kernel(
    const int* __restrict__ sf, const float* __restrict__ dense,
    const int* __restrict__ hist, const float* __restrict__ W,
    const u16* __restrict__ w1h, const u16* __restrict__ w1l,
    const u16* __restrict__ w2h, const u16* __restrict__ w2l,
    const float* __restrict__ b1, const float* __restrict__ b2,
    const float* __restrict__ w3, const float* __restrict__ b3,
    float* __restrict__ out) {
  __shared__ u16 sm[16384];        // A1(h|l) -> A2(h|l) -> out2(f32), reused
  __shared__ float psum[32 * 33];  // history partials, padded stride 33
  const int tid = threadIdx.x;
  const int row0 = blockIdx.x * BM;

  short8v z8 = {0, 0, 0, 0, 0, 0, 0, 0};
  // zero A1 (2048 16B blobs, 512 threads x 4)
#pragma unroll
  for (int i = 0; i < 4; ++i) *(short8v*)&sm[(tid + i * 512) * 8] = z8;
  __syncthreads();

  u16* A1h = sm;         // [2][8][64][8]
  u16* A1l = sm + 8192;  // [2][8][64][8]

  // ---- gather phase (balanced: 256 thr history split-2, 256 thr embeddings) ----
  if (tid < 256) {
    // history: 2 threads per (row, quad); each sums 25 gathers
    int r = tid >> 3, rem = tid & 7, q = rem >> 1, s = rem & 1;
    int rg = row0 + r;
    float a0 = 0.f, a1 = 0.f, a2 = 0.f, a3 = 0.f;
    const int* hp = hist + rg * 50 + s * 25;
#pragma unroll 8
    for (int h = 0; h < 25; ++h) {
      int idx = hp[h] + 1;  // in [1, 100000]; W0 row 0 never hit
      const float* p = W + (size_t)idx * 16 + q * 4;
      a0 += p[0];
      a1 += p[1];
      a2 += p[2];
      a3 += p[3];
    }
    float* ps = &psum[r * 33 + (q * 4) * 2 + s];
    ps[0] = a0;
    ps[2] = a1;
    ps[4] = a2;
    ps[6] = a3;
  } else {
    // embeddings: 1792 quad-gathers over 256 threads (7 independent each)
    int tid2 = tid - 256;
#pragma unroll
    for (int it = 0; it < 7; ++it) {
      int g = tid2 + it * 256;  // < 1792
      int q = g & 3, rt = g >> 2;
      int r = rt & 31, t = rt >> 5;
      int rg = row0 + r;
      int idx = sf[rg * 14 + t] + 1;
      const float* p = W + ((size_t)t * 100001 + (size_t)idx) * 16 + q * 4;
      float v0 = p[0], v1 = p[1], v2 = p[2], v3 = p[3];
      int kb = t * 16 + q * 4;
      wrA1(A1h, A1l, r, kb + 0, v0);
      wrA1(A1h, A1l, r, kb + 1, v1);
      wrA1(A1h, A1l, r, kb + 2, v2);
      wrA1(A1h, A1l, r, kb + 3, v3);
    }
  }
  __syncthreads();

  // combine history partials -> A1 (k = 224..240)
  if (tid < 128) {
    int r = tid >> 2, q = tid & 3;
#pragma unroll
    for (int d = 0; d < 4; ++d) {
      float v = psum[r * 33 + (q * 4 + d) * 2 + 0] + psum[r * 33 + (q * 4 + d) * 2 + 1];
      wrA1(A1h, A1l, r, 224 + q * 4 + d, v);
    }
    if (q == 0) wrA1(A1h, A1l, r, 240, dense[row0 + r]);
  }
  __syncthreads();

  // ---- GEMM1: 8 waves; wave = rh(2) x pg(4); nt = pg + 4*j, j<4 ----
  const int l = tid & 63;
  const int wv = tid >> 6;
  const int rh = wv & 1;
  const int pg = wv >> 1;

  floatx4 acc[4];
#pragma unroll
  for (int i = 0; i < 4; ++i) acc[i] = (floatx4){0.f, 0.f, 0.f, 0.f};

  // A prefetch (1 kt ahead), B depth-4 rotation over flat f = kt*4 + j
  short8v ahr[2], alr[2];
  ahr[0] = *(const short8v*)&A1h[((rh * 8 + 0) * 64 + l) * 8];
  alr[0] = *(const short8v*)&A1l[((rh * 8 + 0) * 64 + l) * 8];

  short8v bhr[4], blr[4];
#pragma unroll
  for (int s = 0; s < 4; ++s) {
    int nt = pg + s * 4;
    if (nt < 13) {
      bhr[s] = *(const short8v*)&w1h[((nt * 8 + 0) * 64 + l) * 8];
      blr[s] = *(const short8v*)&w1l[((nt * 8 + 0) * 64 + l) * 8];
    } else {
      bhr[s] = z8;
      blr[s] = z8;
    }
  }

#pragma unroll
  for (int kt = 0; kt < 8; ++kt) {
    if (kt < 7) {
      ahr[(kt + 1) & 1] = *(const short8v*)&A1h[((rh * 8 + kt + 1) * 64 + l) * 8];
      alr[(kt + 1) & 1] = *(const short8v*)&A1l[((rh * 8 + kt + 1) * 64 + l) * 8];
    }
    short8v ah = ahr[kt & 1], al = alr[kt & 1];
#pragma unroll
    for (int j = 0; j < 4; ++j) {
      int f = kt * 4 + j;
      int nt = pg + j * 4;
      short8v cbh = bhr[f & 3], cbl = blr[f & 3];
      int f4 = f + 4;
      if (f4 < 32) {  // prefetch (kt+1, j) into the slot just consumed
        int nt2 = pg + (f4 & 3) * 4;
        int kt2 = f4 >> 2;
        if (nt2 < 13) {
          bhr[f & 3] = *(const short8v*)&w1h[((nt2 * 8 + kt2) * 64 + l) * 8];
          blr[f & 3] = *(const short8v*)&w1l[((nt2 * 8 + kt2) * 64 + l) * 8];
        }
      }
      if (nt < 13) {
        acc[j] = __builtin_amdgcn_mfma_f32_16x16x32_bf16(ah, cbh, acc[j], 0, 0, 0);
        acc[j] = __builtin_amdgcn_mfma_f32_16x16x32_bf16(al, cbh, acc[j], 0, 0, 0);
        acc[j] = __builtin_amdgcn_mfma_f32_16x16x32_bf16(ah, cbl, acc[j], 0, 0, 0);
      }
    }
  }
  __syncthreads();

  // zero A2 region (1792 blobs)
#pragma unroll
  for (int i = 0; i < 4; ++i) {
    int b = tid + i * 512;
    if (b < 1792) *(short8v*)&sm[b * 8] = z8;
  }
  __syncthreads();

  u16* A2h = sm;         // [2][7][64][8]
  u16* A2l = sm + 7168;  // [2][7][64][8]

  // epilogue1: bias + relu -> A2 fragments. C layout: col=lane&15, row=(lane>>4)*4+reg
#pragma unroll
  for (int j = 0; j < 4; ++j) {
    int nt = pg + j * 4;
    if (nt < 13) {
      int n = nt * 16 + (l & 15);
      if (n < 200) {
        float bias = b1[n];
#pragma unroll
        for (int rg_ = 0; rg_ < 4; ++rg_) {
          float v = fmaxf(acc[j][rg_] + bias, 0.f);
          int m = (l >> 4) * 4 + rg_;
          u16 hi = f2bf(v);
          u16 lo = f2bf(v - bf2f(hi));
          int kt = n >> 5, kg = (n >> 3) & 3, e = n & 7;
          int lane2 = kg * 16 + m;
          int idx = ((rh * 7 + kt) * 64 + lane2) * 8 + e;
          A2h[idx] = hi;
          A2l[idx] = lo;
        }
      }
    }
  }
  __syncthreads();

  // ---- GEMM2: nt = pg + 4*j, j<2 (nt<5) ----
  floatx4 acc2[2];
#pragma unroll
  for (int i = 0; i < 2; ++i) acc2[i] = (floatx4){0.f, 0.f, 0.f, 0.f};

  short8v a2hr[2], a2lr[2];
  a2hr[0] = *(const short8v*)&A2h[((rh * 7 + 0) * 64 + l) * 8];
  a2lr[0] = *(const short8v*)&A2l[((rh * 7 + 0) * 64 + l) * 8];

  short8v b2hr[2], b2lr[2];
#pragma unroll
  for (int s = 0; s < 2; ++s) {
    int nt = pg + s * 4;
    if (nt < 5) {
      b2hr[s] = *(const short8v*)&w2h[((nt * 7 + 0) * 64 + l) * 8];
      b2lr[s] = *(const short8v*)&w2l[((nt * 7 + 0) * 64 + l) * 8];
    } else {
      b2hr[s] = z8;
      b2lr[s] = z8;
    }
  }

#pragma unroll
  for (int kt = 0; kt < 7; ++kt) {
    if (kt < 6) {
      a2hr[(kt + 1) & 1] = *(const short8v*)&A2h[((rh * 7 + kt + 1) * 64 + l) * 8];
      a2lr[(kt + 1) & 1] = *(const short8v*)&A2l[((rh * 7 + kt + 1) * 64 + l) * 8];
    }
    short8v ah = a2hr[kt & 1], al = a2lr[kt & 1];
#pragma unroll
    for (int j = 0; j < 2; ++j) {
      int f = kt * 2 + j;
      int nt = pg + j * 4;
      short8v cbh = b2hr[f & 1], cbl = b2lr[f & 1];
      int f2 = f + 2;
      if (f2 < 14) {
        int nt2 = pg + (f2 & 1) * 4;
        int kt2 = f2 >> 1;
        if (nt2 < 5) {
          b2hr[f & 1] = *(const short8v*)&w2h[((nt2 * 7 + kt2) * 64 + l) * 8];
          b2lr[f & 1] = *(const short8v*)&w2l[((nt2 * 7 + kt2) * 64 + l) * 8];
        }
      }
      if (nt < 5) {
        acc2[j] = __builtin_amdgcn_mfma_f32_16x16x32_bf16(ah, cbh, acc2[j], 0, 0, 0);
        acc2[j] = __builtin_amdgcn_mfma_f32_16x16x32_bf16(al, cbh, acc2[j], 0, 0, 0);
        acc2[j] = __builtin_amdgcn_mfma_f32_16x16x32_bf16(ah, cbl, acc2[j], 0, 0, 0);
      }
    }
  }
  __syncthreads();

  // epilogue2: bias + relu -> out2 f32 LDS [32][81] (padded stride)
  float* o2 = (float*)sm;
#pragma unroll
  for (int j = 0; j < 2; ++j) {
    int nt = pg + j * 4;
    if (nt < 5) {
      int n = nt * 16 + (l & 15);  // < 80
      float bias = b2[n];
#pragma unroll
      for (int rg_ = 0; rg_ < 4; ++rg_) {
        int r = rh * 16 + (l >> 4) * 4 + rg_;
        float v = fmaxf(acc2[j][rg_] + bias, 0.f);
        o2[r * 81 + n] = v;
      }
    }
  }
  __syncthreads();

  // ---- fc3 (fp32 VALU) ----
  if (tid < 64) {
    int r = tid >> 1, o = tid & 1;
    float a = b3[o];
#pragma unroll 8
    for (int j = 0; j < 80; ++j) a += o2[r * 81 + j] * w3[o * 80 + j];
    out[(row0 + r) * 2 + o] = a;
  }
}

extern "C" void kernel_launch(void* const* d_in, const int* in_sizes, int n_in,
                              void* d_out, int out_size, void* d_ws, size_t ws_size,
                              hipStream_t stream) {
  const int* sf = (const int*)d_in[0];
  const float* dense = (const float*)d_in[1];
  const int* hist = (const int*)d_in[2];
  const float* W = (const float*)d_in[3];
  const float* w1 = (const float*)d_in[4];
  const float* b1 = (const float*)d_in[5];
  const float* w2 = (const float*)d_in[6];
  const float* b2 = (const float*)d_in[7];
  const float* w3 = (const float*)d_in[8];
  const float* b3 = (const float*)d_in[9];
  float* out = (float*)d_out;

  // ws: w1h | w1l | w2h | w2l  (284,672 bytes total)
  u16* w1h = (u16*)d_ws;
  u16* w1l = w1h + W1_ELEMS;
  u16* w2h = w1l + W1_ELEMS;
  u16* w2l = w2h + W2_ELEMS;

  build_frags<<<dim3(35), dim3(256), 0, stream>>>(w1, w2, w1h, w1l, w2h, w2l);
  fused_kernel<<<dim3(NBLK), dim3(512), 0, stream>>>(sf, dense, hist, W, w1h, w1l, w2h, w2l,
                                                     b1, b2, w3, b3, out);
}

// Round 3
// 30.922 us; speedup vs baseline: 1.7162x; 1.1826x over previous
//
#include <hip/hip_runtime.h>

// RecModel fused kernel — round 3.
// Changes vs round 2: 1024-thread blocks (32 waves/CU), 2-term split product
// (A hi/lo x B bf16 — weight-lo dropped), early B prefetch, launch_bounds(1024,8).

using u16 = unsigned short;
typedef __attribute__((ext_vector_type(8))) short short8v;
typedef __attribute__((ext_vector_type(4))) float floatx4;

constexpr int BM = 32;            // rows per block
constexpr int NBLK = 16384 / BM;  // 512

// ws layout (elements of u16)
constexpr int W1_ELEMS = 13 * 8 * 64 * 8;  // 53248
constexpr int W2_ELEMS = 5 * 7 * 64 * 8;   // 17920

__device__ __forceinline__ u16 f2bf(float f) {
  unsigned u = __float_as_uint(f);
  unsigned r = (u + 0x7fffu + ((u >> 16) & 1u)) >> 16;  // RN-even
  return (u16)r;
}
__device__ __forceinline__ float bf2f(u16 h) {
  return __uint_as_float(((unsigned)h) << 16);
}

// write one x value into A1 fragment layout: lane = kg*16 + (r&15) holds k = kt*32+kg*8+e
__device__ __forceinline__ void wrA1(u16* Ah, u16* Al, int r, int k, float v) {
  u16 hi = f2bf(v);
  u16 lo = f2bf(v - bf2f(hi));
  int kt = k >> 5, kg = (k >> 3) & 3, e = k & 7;
  int lane = kg * 16 + (r & 15);
  int idx = (((r >> 4) * 8 + kt) * 64 + lane) * 8 + e;
  Ah[idx] = hi;
  Al[idx] = lo;
}

// ---- precompute: fc1/fc2 weights -> bf16 fragment arrays in ws ----
__global__ void build_frags(const float* __restrict__ w1, const float* __restrict__ w2,
                            u16* __restrict__ w1h, u16* __restrict__ w2h) {
  int tid = blockIdx.x * blockDim.x + threadIdx.x;
  if (tid < 13 * 8 * 64) {  // fc1 frags
    int l = tid & 63;
    int g = tid >> 6;
    int kt = g & 7, nt = g >> 3;
    int n = nt * 16 + (l & 15);
    int kb = kt * 32 + (l >> 4) * 8;
    short8v h8;
#pragma unroll
    for (int e = 0; e < 8; ++e) {
      int k = kb + e;
      float v = (n < 200 && k < 241) ? w1[n * 241 + k] : 0.f;
      h8[e] = (short)f2bf(v);
    }
    *(short8v*)&w1h[tid * 8] = h8;
  } else if (tid < 13 * 8 * 64 + 5 * 7 * 64) {  // fc2 frags
    int t2 = tid - 13 * 8 * 64;
    int l = t2 & 63;
    int g = t2 >> 6;
    int kt = g % 7, nt = g / 7;
    int n = nt * 16 + (l & 15);  // < 80
    int kb = kt * 32 + (l >> 4) * 8;
    short8v h8;
#pragma unroll
    for (int e = 0; e < 8; ++e) {
      int k = kb + e;
      float v = (k < 200) ? w2[n * 200 + k] : 0.f;
      h8[e] = (short)f2bf(v);
    }
    *(short8v*)&w2h[t2 * 8] = h8;
  }
}

// ---- main fused kernel: 1024 threads = 16 waves: wv = rh(2) x pg(8) ----
__global__ __launch_bounds__(1024, 8) void fused_kernel(
    const int* __restrict__ sf, const float* __restrict__ dense,
    const int* __restrict__ hist, const float* __restrict__ W,
    const u16* __restrict__ w1h, const u16* __restrict__ w2h,
    const float* __restrict__ b1, const float* __restrict__ b2,
    const float* __restrict__ w3, const float* __restrict__ b3,
    float* __restrict__ out) {
  __shared__ u16 sm[16384];        // A1(h|l) -> A2(h|l) -> out2(f32), reused
  __shared__ float psum[32 * 68];  // history partials: r*68 + d*4 + s
  const int tid = threadIdx.x;
  const int row0 = blockIdx.x * BM;
  const int l = tid & 63;
  const int wv = tid >> 6;
  const int rh = wv & 1;
  const int pg = wv >> 1;  // 0..7

  short8v z8 = {0, 0, 0, 0, 0, 0, 0, 0};

  // early prefetch of GEMM1 B (kt=0, both j slots) — independent of gather
  short8v bhr[2];
#pragma unroll
  for (int s = 0; s < 2; ++s) {
    int nt = pg + 8 * s;
    bhr[s] = (nt < 13) ? *(const short8v*)&w1h[((nt * 8 + 0) * 64 + l) * 8] : z8;
  }

  // zero A1 (2048 16B blobs, 1024 threads x 2)
#pragma unroll
  for (int i = 0; i < 2; ++i) *(short8v*)&sm[(tid + i * 1024) * 8] = z8;
  __syncthreads();

  u16* A1h = sm;         // [2][8][64][8]
  u16* A1l = sm + 8192;  // [2][8][64][8]

  // ---- gather phase: 512 thr history (4-way split), 512 thr embeddings ----
  if (tid < 512) {
    // history: 16 threads per row: (q dim-quad, s 4-way split of 50)
    int r = tid >> 4, rem = tid & 15, q = rem >> 2, s = rem & 3;
    int rg = row0 + r;
    int beg = s * 12 + (s < 2 ? s : 2);       // 0,13,26,38
    int cnt = 12 + (s < 2 ? 1 : 0);           // 13,13,12,12
    float a0 = 0.f, a1 = 0.f, a2 = 0.f, a3 = 0.f;
    const int* hp = hist + rg * 50;
#pragma unroll 4
    for (int h = beg; h < beg + cnt; ++h) {
      int idx = hp[h] + 1;  // in [1, 100000]; W0 row 0 never hit
      const float* p = W + (size_t)idx * 16 + q * 4;
      a0 += p[0];
      a1 += p[1];
      a2 += p[2];
      a3 += p[3];
    }
    float* ps = &psum[r * 68 + (q * 4) * 4 + s];
    ps[0] = a0;
    ps[4] = a1;
    ps[8] = a2;
    ps[12] = a3;
  } else {
    // embeddings: 1792 quad-gathers over 512 threads
    int tid2 = tid - 512;
#pragma unroll
    for (int it = 0; it < 4; ++it) {
      int g = tid2 + it * 512;
      if (g < 1792) {
        int q = g & 3, rt = g >> 2;
        int r = rt & 31, t = rt >> 5;
        int rg = row0 + r;
        int idx = sf[rg * 14 + t] + 1;
        const float* p = W + ((size_t)t * 100001 + (size_t)idx) * 16 + q * 4;
        float v0 = p[0], v1 = p[1], v2 = p[2], v3 = p[3];
        int kb = t * 16 + q * 4;
        wrA1(A1h, A1l, r, kb + 0, v0);
        wrA1(A1h, A1l, r, kb + 1, v1);
        wrA1(A1h, A1l, r, kb + 2, v2);
        wrA1(A1h, A1l, r, kb + 3, v3);
      }
    }
  }
  __syncthreads();

  // combine history partials -> A1 (k = 224..239), dense -> k=240
  if (tid < 512) {
    int r = tid >> 4, d = tid & 15;
    const float* ps = &psum[r * 68 + d * 4];
    float v = ps[0] + ps[1] + ps[2] + ps[3];
    wrA1(A1h, A1l, r, 224 + d, v);
    if (d == 0) wrA1(A1h, A1l, r, 240, dense[row0 + r]);
  }
  __syncthreads();

  // ---- GEMM1: nt = pg + 8j, j<2 (13 nt tiles) ----
  floatx4 acc[2];
#pragma unroll
  for (int i = 0; i < 2; ++i) acc[i] = (floatx4){0.f, 0.f, 0.f, 0.f};

#pragma unroll
  for (int kt = 0; kt < 8; ++kt) {
    short8v ah = *(const short8v*)&A1h[((rh * 8 + kt) * 64 + l) * 8];
    short8v al = *(const short8v*)&A1l[((rh * 8 + kt) * 64 + l) * 8];
#pragma unroll
    for (int j = 0; j < 2; ++j) {
      int f = kt * 2 + j;
      int nt = pg + 8 * j;
      short8v cbh = bhr[j];
      int f2 = f + 2;
      if (f2 < 16) {  // prefetch (kt+1, j) into slot j
        int nt2 = pg + 8 * (f2 & 1);
        int kt2 = f2 >> 1;
        if (nt2 < 13) bhr[j] = *(const short8v*)&w1h[((nt2 * 8 + kt2) * 64 + l) * 8];
      }
      if (nt < 13) {
        acc[j] = __builtin_amdgcn_mfma_f32_16x16x32_bf16(ah, cbh, acc[j], 0, 0, 0);
        acc[j] = __builtin_amdgcn_mfma_f32_16x16x32_bf16(al, cbh, acc[j], 0, 0, 0);
      }
    }
  }
  __syncthreads();

  // zero A2 region (1792 blobs)
#pragma unroll
  for (int i = 0; i < 2; ++i) {
    int b = tid + i * 1024;
    if (b < 1792) *(short8v*)&sm[b * 8] = z8;
  }
  __syncthreads();

  u16* A2h = sm;         // [2][7][64][8]
  u16* A2l = sm + 7168;  // [2][7][64][8]

  // epilogue1: bias + relu -> A2 fragments. C layout: col=lane&15, row=(lane>>4)*4+reg
#pragma unroll
  for (int j = 0; j < 2; ++j) {
    int nt = pg + 8 * j;
    if (nt < 13) {
      int n = nt * 16 + (l & 15);
      if (n < 200) {
        float bias = b1[n];
#pragma unroll
        for (int rg_ = 0; rg_ < 4; ++rg_) {
          float v = fmaxf(acc[j][rg_] + bias, 0.f);
          int m = (l >> 4) * 4 + rg_;
          u16 hi = f2bf(v);
          u16 lo = f2bf(v - bf2f(hi));
          int kt = n >> 5, kg = (n >> 3) & 3, e = n & 7;
          int lane2 = kg * 16 + m;
          int idx = ((rh * 7 + kt) * 64 + lane2) * 8 + e;
          A2h[idx] = hi;
          A2l[idx] = lo;
        }
      }
    }
  }
  __syncthreads();

  // ---- GEMM2: nt = pg (5 tiles; waves pg>=5 idle) ----
  floatx4 acc2 = (floatx4){0.f, 0.f, 0.f, 0.f};
  if (pg < 5) {
    short8v b2hr[2];
    b2hr[0] = *(const short8v*)&w2h[((pg * 7 + 0) * 64 + l) * 8];
    b2hr[1] = *(const short8v*)&w2h[((pg * 7 + 1) * 64 + l) * 8];
#pragma unroll
    for (int kt = 0; kt < 7; ++kt) {
      short8v ah = *(const short8v*)&A2h[((rh * 7 + kt) * 64 + l) * 8];
      short8v al = *(const short8v*)&A2l[((rh * 7 + kt) * 64 + l) * 8];
      short8v cb = b2hr[kt & 1];
      if (kt + 2 < 7) b2hr[kt & 1] = *(const short8v*)&w2h[((pg * 7 + kt + 2) * 64 + l) * 8];
      acc2 = __builtin_amdgcn_mfma_f32_16x16x32_bf16(ah, cb, acc2, 0, 0, 0);
      acc2 = __builtin_amdgcn_mfma_f32_16x16x32_bf16(al, cb, acc2, 0, 0, 0);
    }
  }
  __syncthreads();

  // epilogue2: bias + relu -> out2 f32 LDS [32][81] (padded stride)
  float* o2 = (float*)sm;
  if (pg < 5) {
    int n = pg * 16 + (l & 15);  // < 80
    float bias = b2[n];
#pragma unroll
    for (int rg_ = 0; rg_ < 4; ++rg_) {
      int r = rh * 16 + (l >> 4) * 4 + rg_;
      float v = fmaxf(acc2[rg_] + bias, 0.f);
      o2[r * 81 + n] = v;
    }
  }
  __syncthreads();

  // ---- fc3 (fp32 VALU) ----
  if (tid < 64) {
    int r = tid >> 1, o = tid & 1;
    float a = b3[o];
#pragma unroll 8
    for (int j = 0; j < 80; ++j) a += o2[r * 81 + j] * w3[o * 80 + j];
    out[(row0 + r) * 2 + o] = a;
  }
}

extern "C" void kernel_launch(void* const* d_in, const int* in_sizes, int n_in,
                              void* d_out, int out_size, void* d_ws, size_t ws_size,
                              hipStream_t stream) {
  const int* sf = (const int*)d_in[0];
  const float* dense = (const float*)d_in[1];
  const int* hist = (const int*)d_in[2];
  const float* W = (const float*)d_in[3];
  const float* w1 = (const float*)d_in[4];
  const float* b1 = (const float*)d_in[5];
  const float* w2 = (const float*)d_in[6];
  const float* b2 = (const float*)d_in[7];
  const float* w3 = (const float*)d_in[8];
  const float* b3 = (const float*)d_in[9];
  float* out = (float*)d_out;

  // ws: w1h | w2h
  u16* w1h = (u16*)d_ws;
  u16* w2h = w1h + W1_ELEMS;

  build_frags<<<dim3(35), dim3(256), 0, stream>>>(w1, w2, w1h, w2h);
  fused_kernel<<<dim3(NBLK), dim3(1024), 0, stream>>>(sf, dense, hist, W, w1h, w2h,
                                                      b1, b2, w3, b3, out);
}